// Round 15
// baseline (79.345 us; speedup 1.0000x reference)
//
#include <hip/hip_runtime.h>
#include <hip/hip_bf16.h>
#include <stdint.h>

// SimCLR loss, n=8192, d=128, T=0.07.
// R15 = R13 base (fragment-major fnB; no LDS/barriers in k_simexp) with:
//  (a) R14 lesson: hipLaunchCooperativeKernel fails in this harness (silent
//      launch error, out never written). Reverted to multi-dispatch.
//  (b) k_reduce fused into k_finalize via last-block-done (device atomic
//      counter + threadfence; no co-residency assumption) -> 3 dispatches.
//  (c) k_simexp: 2 slices per block reusing one Af load (A traffic halves,
//      grid 512, tail-free).
//  k_normalize: fp32 -> bf16 fn (row-major) + fnB (frag-major); resets counter
//  k_simexp:    E_part[row][slice] = sum_j exp2((dot-1)*s)  (plain stores)
//  k_finalize:  per-row term -> terms[]; last block reduces -> out[0]

#define N_ROWS 8192
#define DIM    128
#define HALF_N 4096
#define N_SLICES 32
#define NT 16                     // 16-col tiles per 256-col slice
#define NBLK_FIN (N_ROWS / 4)     // 2048 finalize blocks

static constexpr float INV_T = 14.285714285714286f;   // 1/0.07
static constexpr float SCALE = 20.60992915555662f;    // log2(e)/0.07

typedef __attribute__((ext_vector_type(8))) short short8;   // 8 bf16 = 4 VGPR
typedef __attribute__((ext_vector_type(4))) float f32x4;

#if __has_builtin(__builtin_amdgcn_exp2f)
__device__ inline float fast_exp2(float x) { return __builtin_amdgcn_exp2f(x); }
#else
__device__ inline float fast_exp2(float x) { return exp2f(x); }
#endif

__device__ inline float bf_lo(uint32_t u) { return __uint_as_float(u << 16); }
__device__ inline float bf_hi(uint32_t u) { return __uint_as_float(u & 0xFFFF0000u); }
__device__ inline uint16_t f2bf(float x) {
    uint32_t u = __float_as_uint(x);
    return (uint16_t)((u + 0x7FFFu + ((u >> 16) & 1u)) >> 16);   // RNE
}

// fnB layout (16B chunks): chunk(row j, dim k) = (j>>4)*256 + (k>>5)*64
//   + ((k>>3)&3)*16 + (j&15); byte-in-chunk = (k&7)*2.
// Fragment load for lane l: fnB16[tile*256 + kc*64 + l] = row tile*16+(l&15),
// dims kc*32+(l>>4)*8..+8.  A and B fragments are identical gathers.

// ---------------- kernel 1: normalize -> fn + fnB; reset counter ----------
__global__ __launch_bounds__(256) void k_normalize(const float* __restrict__ f,
                                                   uint16_t* __restrict__ fn,
                                                   uint16_t* __restrict__ fnB,
                                                   int* __restrict__ counter) {
    if (blockIdx.x == 0 && threadIdx.x == 0) counter[0] = 0;
    int wid  = (blockIdx.x * blockDim.x + threadIdx.x) >> 6;   // one wave per row
    int lane = threadIdx.x & 63;
    const float2* src = (const float2*)(f + (size_t)wid * DIM);
    float2 v = src[lane];
    float ss = v.x * v.x + v.y * v.y;
    #pragma unroll
    for (int m = 1; m < 64; m <<= 1) ss += __shfl_xor(ss, m, 64);
    float inv = rsqrtf(ss);
    ushort2 o;
    o.x = f2bf(v.x * inv);
    o.y = f2bf(v.y * inv);
    ((ushort2*)(fn + (size_t)wid * DIM))[lane] = o;              // row-major
    int k0 = lane * 2;                                            // frag-major
    size_t chunk = (size_t)(wid >> 4) * 256 + (k0 >> 5) * 64 +
                   ((k0 >> 3) & 3) * 16 + (wid & 15);
    *(ushort2*)((char*)fnB + chunk * 16 + (k0 & 7) * 2) = o;
}

// ---------------- kernel 2: sim + exp-sum (2 slices per block) ------------
// Grid 512: b&31 -> 256-row group, b>>5 -> slice pair. Wave owns 64 rows.
__global__ __launch_bounds__(256) void k_simexp(const uint16_t* __restrict__ fnB,
                                                float* __restrict__ E_part) {
    const int lane = threadIdx.x & 63;
    const int w    = threadIdx.x >> 6;
    const int b    = blockIdx.x;
    const int lr = lane & 15;
    const int lk = lane >> 4;
    const int ib = (b & 31) * 256 + w * 64;          // wave's 64 rows
    const int sg = b >> 5;                           // slice pair 0..15
    const short8* fnB8 = (const short8*)fnB;
    const int tileA0 = ib >> 4;

    short8 Af[4][4];                                 // loaded once, 2 slices
    #pragma unroll
    for (int mt = 0; mt < 4; ++mt)
        #pragma unroll
        for (int kc = 0; kc < 4; ++kc)
            Af[mt][kc] = fnB8[(size_t)(tileA0 + mt) * 256 + kc * 64 + lane];

    #pragma unroll
    for (int half = 0; half < 2; ++half) {
        const int slice = sg * 2 + half;
        const short8* bbase = fnB8 + (size_t)slice * NT * 256 + lane;
        float es[4][4];
        #pragma unroll
        for (int mt = 0; mt < 4; ++mt)
            #pragma unroll
            for (int r = 0; r < 4; ++r) es[mt][r] = 0.0f;

        for (int jt = 0; jt < NT; ++jt) {
            const short8* bp = bbase + (size_t)jt * 256;
            short8 Bf[4];
            #pragma unroll
            for (int kc = 0; kc < 4; ++kc)
                Bf[kc] = bp[kc * 64];                // coalesced 1KB per load
            #pragma unroll
            for (int mt = 0; mt < 4; ++mt) {
                f32x4 acc = {0.0f, 0.0f, 0.0f, 0.0f};
                #pragma unroll
                for (int kc = 0; kc < 4; ++kc)
                    acc = __builtin_amdgcn_mfma_f32_16x16x32_bf16(Af[mt][kc], Bf[kc], acc, 0, 0, 0);
                #pragma unroll
                for (int r = 0; r < 4; ++r)
                    es[mt][r] += fast_exp2(fmaf(acc[r], SCALE, -SCALE));
            }
        }
        // C/D: col = lane&15, row = lk*4 + r. Reduce over 16 col-lanes.
        #pragma unroll
        for (int mt = 0; mt < 4; ++mt)
            #pragma unroll
            for (int r = 0; r < 4; ++r) {
                float v = es[mt][r];
                v += __shfl_xor(v, 1, 64);
                v += __shfl_xor(v, 2, 64);
                v += __shfl_xor(v, 4, 64);
                v += __shfl_xor(v, 8, 64);
                if (lr == 0)
                    E_part[(size_t)(ib + mt * 16 + lk * 4 + r) * N_SLICES + slice] = v;
            }
    }
}

// ---------------- kernel 3: finalize; last block reduces -> out -----------
__global__ __launch_bounds__(256) void k_finalize(const uint16_t* __restrict__ fn,
                                                  const float* __restrict__ E_part,
                                                  float* __restrict__ terms,
                                                  int* __restrict__ counter,
                                                  float* __restrict__ out) {
    __shared__ float sm[4];
    __shared__ int is_last;
    const int tid  = threadIdx.x;
    int wid  = (blockIdx.x * blockDim.x + tid) >> 6;   // one wave per row
    int lane = tid & 63;
    int partner = (wid + HALF_N) & (N_ROWS - 1);
    const uint32_t* fr = (const uint32_t*)(fn + (size_t)wid * DIM);
    const uint32_t* pr = (const uint32_t*)(fn + (size_t)partner * DIM);
    uint32_t a = fr[lane], p = pr[lane];
    float a0 = bf_lo(a), a1 = bf_hi(a);
    float p0 = bf_lo(p), p1 = bf_hi(p);
    float sd = a0 * a0 + a1 * a1;       // self dot (diagonal recompute)
    float pd = a0 * p0 + a1 * p1;       // positive-pair dot
    #pragma unroll
    for (int m = 1; m < 64; m <<= 1) {
        sd += __shfl_xor(sd, m, 64);
        pd += __shfl_xor(pd, m, 64);
    }
    float e = (lane < N_SLICES) ? E_part[(size_t)wid * N_SLICES + lane] : 0.0f;
    #pragma unroll
    for (int m = 1; m < 64; m <<= 1) e += __shfl_xor(e, m, 64);
    if (lane == 0) {
        float ep = e - fast_exp2(fmaf(sd, SCALE, -SCALE));   // remove diagonal
        sm[tid >> 6] = INV_T + logf(ep) - pd * INV_T;
    }
    __syncthreads();
    if (tid == 0) {
        terms[blockIdx.x] = sm[0] + sm[1] + sm[2] + sm[3];
        __threadfence();                                 // publish terms
        int old = atomicAdd(counter, 1);                 // device-scope
        is_last = (old == NBLK_FIN - 1);
    }
    __syncthreads();
    if (is_last) {                                       // one block total
        __threadfence();                                 // acquire all terms
        float acc = 0.0f;
        for (int i = tid; i < NBLK_FIN; i += 256) acc += terms[i];
        #pragma unroll
        for (int m = 1; m < 64; m <<= 1) acc += __shfl_xor(acc, m, 64);
        __syncthreads();                                 // sm reuse
        if (lane == 0) sm[tid >> 6] = acc;
        __syncthreads();
        if (tid == 0)
            out[0] = (sm[0] + sm[1] + sm[2] + sm[3]) * (1.0f / N_ROWS);
    }
}

extern "C" void kernel_launch(void* const* d_in, const int* in_sizes, int n_in,
                              void* d_out, int out_size, void* d_ws, size_t ws_size,
                              hipStream_t stream) {
    const float* feat = (const float*)d_in[0];
    float* out = (float*)d_out;

    // ws: fn (2 MiB) | fnB (2 MiB) | E_part (1 MiB) | terms (8 KiB) | counter
    uint16_t* fn  = (uint16_t*)d_ws;
    uint16_t* fnB = fn + (size_t)N_ROWS * DIM;
    float* E_part = (float*)(fnB + (size_t)N_ROWS * DIM);
    float* terms  = E_part + (size_t)N_ROWS * N_SLICES;
    int* counter  = (int*)(terms + NBLK_FIN);

    k_normalize<<<dim3(N_ROWS / 4), dim3(256), 0, stream>>>(feat, fn, fnB, counter);
    k_simexp<<<dim3(512), dim3(256), 0, stream>>>(fnB, E_part);
    k_finalize<<<dim3(NBLK_FIN), dim3(256), 0, stream>>>(fn, E_part, terms, counter, out);
}

// Round 16
// 42.961 us; speedup vs baseline: 1.8469x; 1.8469x over previous
//
#include <hip/hip_runtime.h>
#include <hip/hip_bf16.h>
#include <stdint.h>

// SimCLR loss, n=8192, d=128, T=0.07.
// R16 = R13 skeleton (4 dispatches; fragment-major fnB; no LDS/barriers/
// atomics in k_simexp; terms[] + single-block k_reduce) + R15's good part:
// k_simexp does 2 slices per block reusing ONE Af load (A traffic halves,
// grid 512, tail-free).
// R15 lesson (locked): last-block-done = 2048 same-address atomicAdd +
// per-block threadfence = 44us finalize (R10's sin in disguise). The final
// scalar reduction gets its own tiny dispatch, period.
//  k_normalize: fp32 -> bf16: fn (row-major) + fnB (fragment-major)
//  k_simexp:    E_part[row][slice] = sum_j exp2((dot-1)*s)  (plain stores)
//  k_finalize:  per-row term -> terms[];  k_reduce: mean -> out[0]

#define N_ROWS 8192
#define DIM    128
#define HALF_N 4096
#define N_SLICES 32
#define NT 16                     // 16-col tiles per 256-col slice

static constexpr float INV_T = 14.285714285714286f;   // 1/0.07
static constexpr float SCALE = 20.60992915555662f;    // log2(e)/0.07

typedef __attribute__((ext_vector_type(8))) short short8;   // 8 bf16 = 4 VGPR
typedef __attribute__((ext_vector_type(4))) float f32x4;

#if __has_builtin(__builtin_amdgcn_exp2f)
__device__ inline float fast_exp2(float x) { return __builtin_amdgcn_exp2f(x); }
#else
__device__ inline float fast_exp2(float x) { return exp2f(x); }
#endif

__device__ inline float bf_lo(uint32_t u) { return __uint_as_float(u << 16); }
__device__ inline float bf_hi(uint32_t u) { return __uint_as_float(u & 0xFFFF0000u); }
__device__ inline uint16_t f2bf(float x) {
    uint32_t u = __float_as_uint(x);
    return (uint16_t)((u + 0x7FFFu + ((u >> 16) & 1u)) >> 16);   // RNE
}

// fnB layout (16B chunks): chunk(row j, dim k) = (j>>4)*256 + (k>>5)*64
//   + ((k>>3)&3)*16 + (j&15); byte-in-chunk = (k&7)*2.
// Fragment load for lane l: fnB16[tile*256 + kc*64 + l] = row tile*16+(l&15),
// dims kc*32+(l>>4)*8..+8.  A and B fragments are identical gathers.

// ---------------- kernel 1: normalize -> fn (row-major) + fnB (frag) ------
__global__ __launch_bounds__(256) void k_normalize(const float* __restrict__ f,
                                                   uint16_t* __restrict__ fn,
                                                   uint16_t* __restrict__ fnB) {
    int wid  = (blockIdx.x * blockDim.x + threadIdx.x) >> 6;   // one wave per row
    int lane = threadIdx.x & 63;
    const float2* src = (const float2*)(f + (size_t)wid * DIM);
    float2 v = src[lane];
    float ss = v.x * v.x + v.y * v.y;
    #pragma unroll
    for (int m = 1; m < 64; m <<= 1) ss += __shfl_xor(ss, m, 64);
    float inv = rsqrtf(ss);
    ushort2 o;
    o.x = f2bf(v.x * inv);
    o.y = f2bf(v.y * inv);
    ((ushort2*)(fn + (size_t)wid * DIM))[lane] = o;              // row-major
    int k0 = lane * 2;                                            // frag-major
    size_t chunk = (size_t)(wid >> 4) * 256 + (k0 >> 5) * 64 +
                   ((k0 >> 3) & 3) * 16 + (wid & 15);
    *(ushort2*)((char*)fnB + chunk * 16 + (k0 & 7) * 2) = o;
}

// ---------------- kernel 2: sim + exp-sum (2 slices per block) ------------
// Grid 512: b&31 -> 256-row group, b>>5 -> slice pair. Wave owns 64 rows.
__global__ __launch_bounds__(256) void k_simexp(const uint16_t* __restrict__ fnB,
                                                float* __restrict__ E_part) {
    const int lane = threadIdx.x & 63;
    const int w    = threadIdx.x >> 6;
    const int b    = blockIdx.x;
    const int lr = lane & 15;
    const int lk = lane >> 4;
    const int ib = (b & 31) * 256 + w * 64;          // wave's 64 rows
    const int sg = b >> 5;                           // slice pair 0..15
    const short8* fnB8 = (const short8*)fnB;
    const int tileA0 = ib >> 4;

    short8 Af[4][4];                                 // loaded once, 2 slices
    #pragma unroll
    for (int mt = 0; mt < 4; ++mt)
        #pragma unroll
        for (int kc = 0; kc < 4; ++kc)
            Af[mt][kc] = fnB8[(size_t)(tileA0 + mt) * 256 + kc * 64 + lane];

    #pragma unroll
    for (int half = 0; half < 2; ++half) {
        const int slice = sg * 2 + half;
        const short8* bbase = fnB8 + (size_t)slice * NT * 256 + lane;
        float es[4][4];
        #pragma unroll
        for (int mt = 0; mt < 4; ++mt)
            #pragma unroll
            for (int r = 0; r < 4; ++r) es[mt][r] = 0.0f;

        for (int jt = 0; jt < NT; ++jt) {
            const short8* bp = bbase + (size_t)jt * 256;
            short8 Bf[4];
            #pragma unroll
            for (int kc = 0; kc < 4; ++kc)
                Bf[kc] = bp[kc * 64];                // coalesced 1KB per load
            #pragma unroll
            for (int mt = 0; mt < 4; ++mt) {
                f32x4 acc = {0.0f, 0.0f, 0.0f, 0.0f};
                #pragma unroll
                for (int kc = 0; kc < 4; ++kc)
                    acc = __builtin_amdgcn_mfma_f32_16x16x32_bf16(Af[mt][kc], Bf[kc], acc, 0, 0, 0);
                #pragma unroll
                for (int r = 0; r < 4; ++r)
                    es[mt][r] += fast_exp2(fmaf(acc[r], SCALE, -SCALE));
            }
        }
        // C/D: col = lane&15, row = lk*4 + r. Reduce over 16 col-lanes.
        #pragma unroll
        for (int mt = 0; mt < 4; ++mt)
            #pragma unroll
            for (int r = 0; r < 4; ++r) {
                float v = es[mt][r];
                v += __shfl_xor(v, 1, 64);
                v += __shfl_xor(v, 2, 64);
                v += __shfl_xor(v, 4, 64);
                v += __shfl_xor(v, 8, 64);
                if (lr == 0)
                    E_part[(size_t)(ib + mt * 16 + lk * 4 + r) * N_SLICES + slice] = v;
            }
    }
}

// ---------------- kernel 3: per-row finalize -> block partials ------------
__global__ __launch_bounds__(256) void k_finalize(const uint16_t* __restrict__ fn,
                                                  const float* __restrict__ E_part,
                                                  float* __restrict__ terms) {
    __shared__ float sm[4];
    int wid  = (blockIdx.x * blockDim.x + threadIdx.x) >> 6;   // one wave per row
    int lane = threadIdx.x & 63;
    int partner = (wid + HALF_N) & (N_ROWS - 1);
    const uint32_t* fr = (const uint32_t*)(fn + (size_t)wid * DIM);
    const uint32_t* pr = (const uint32_t*)(fn + (size_t)partner * DIM);
    uint32_t a = fr[lane], p = pr[lane];
    float a0 = bf_lo(a), a1 = bf_hi(a);
    float p0 = bf_lo(p), p1 = bf_hi(p);
    float sd = a0 * a0 + a1 * a1;       // self dot (diagonal recompute)
    float pd = a0 * p0 + a1 * p1;       // positive-pair dot
    #pragma unroll
    for (int m = 1; m < 64; m <<= 1) {
        sd += __shfl_xor(sd, m, 64);
        pd += __shfl_xor(pd, m, 64);
    }
    float e = (lane < N_SLICES) ? E_part[(size_t)wid * N_SLICES + lane] : 0.0f;
    #pragma unroll
    for (int m = 1; m < 64; m <<= 1) e += __shfl_xor(e, m, 64);
    if (lane == 0) {
        float ep = e - fast_exp2(fmaf(sd, SCALE, -SCALE));   // remove diagonal
        sm[threadIdx.x >> 6] = INV_T + logf(ep) - pd * INV_T;
    }
    __syncthreads();
    if (threadIdx.x == 0)
        terms[blockIdx.x] = sm[0] + sm[1] + sm[2] + sm[3];
}

// ---------------- kernel 4: mean over 2048 block partials ----------------
__global__ __launch_bounds__(256) void k_reduce(const float* __restrict__ terms,
                                                float* __restrict__ out) {
    __shared__ float sm[4];
    float acc = 0.0f;
    for (int i = threadIdx.x; i < N_ROWS / 4; i += 256) acc += terms[i];
    #pragma unroll
    for (int m = 1; m < 64; m <<= 1) acc += __shfl_xor(acc, m, 64);
    if ((threadIdx.x & 63) == 0) sm[threadIdx.x >> 6] = acc;
    __syncthreads();
    if (threadIdx.x == 0)
        out[0] = (sm[0] + sm[1] + sm[2] + sm[3]) * (1.0f / N_ROWS);
}

extern "C" void kernel_launch(void* const* d_in, const int* in_sizes, int n_in,
                              void* d_out, int out_size, void* d_ws, size_t ws_size,
                              hipStream_t stream) {
    const float* feat = (const float*)d_in[0];
    float* out = (float*)d_out;

    // ws: fn (2 MiB) | fnB (2 MiB) | E_part (1 MiB) | terms (8 KiB)
    uint16_t* fn  = (uint16_t*)d_ws;
    uint16_t* fnB = fn + (size_t)N_ROWS * DIM;
    float* E_part = (float*)(fnB + (size_t)N_ROWS * DIM);
    float* terms  = E_part + (size_t)N_ROWS * N_SLICES;

    k_normalize<<<dim3(N_ROWS / 4), dim3(256), 0, stream>>>(feat, fn, fnB);
    k_simexp<<<dim3(512), dim3(256), 0, stream>>>(fnB, E_part);
    k_finalize<<<dim3(N_ROWS / 4), dim3(256), 0, stream>>>(fn, E_part, terms);
    k_reduce<<<dim3(1), dim3(256), 0, stream>>>(terms, out);
}